// Round 14
// baseline (119.996 us; speedup 1.0000x reference)
//
#include <hip/hip_runtime.h>

#define NT 64
#define TOK 64   // tokens per wave; one wave per block; grid 2048 = 8 blocks/CU resident

#define GL16(gp, lp) __builtin_amdgcn_global_load_lds( \
    (const __attribute__((address_space(1))) void*)(gp), \
    (__attribute__((address_space(3))) void*)(lp), 16, 0, 0)
#define WAITVM(N) do { \
    asm volatile("s_waitcnt vmcnt(" #N ")" ::: "memory"); \
    __builtin_amdgcn_sched_barrier(0); \
} while (0)
#define WAITLG() do { \
    asm volatile("s_waitcnt lgkmcnt(0)" ::: "memory"); \
    __builtin_amdgcn_sched_barrier(0); \
} while (0)

#if defined(__has_builtin)
# if __has_builtin(__builtin_amdgcn_exp2f)
#  define EXP2F(x) __builtin_amdgcn_exp2f(x)
# else
#  define EXP2F(x) exp2f(x)
# endif
#else
# define EXP2F(x) exp2f(x)
#endif

__device__ __forceinline__ float bf2f(unsigned short u) {
    return __int_as_float(((int)u) << 16);
}
__device__ __forceinline__ unsigned short f2bf(float x) {   // RNE
    unsigned u = __float_as_uint(x);
    return (unsigned short)((u + 0x7FFFu + ((u >> 16) & 1u)) >> 16);
}

// FULL 64 tokens x 45 floats = 720 float4 -> LDS: 11 full GL16 + 16-lane partial = 12 issues.
// (R12/R13 bug: this was the 32-token version; lanes 32-63 projected garbage.)
__device__ __forceinline__ void stage45(const float* __restrict__ g, float* lds, int lane) {
    const float4* g4 = (const float4*)g;
    #pragma unroll
    for (int it = 0; it < 11; ++it)
        GL16(g4 + it * 64 + lane, lds + it * 256);
    if (lane < 16) GL16(g4 + 704 + lane, lds + 2816);
}

// One LINEAR dist chunk = 8 consecutive tokens' full 15x15 blocks = 1800 floats = 450 float4,
// CONTIGUOUS in global memory. 7 full GL16 + one 2-lane partial = 8 issues.
__device__ __forceinline__ void stage_chunk(const float* __restrict__ dr, float* slot, int lane) {
    const float4* g4 = (const float4*)dr;
    #pragma unroll
    for (int it = 0; it < 7; ++it)
        GL16(g4 + it * 64 + lane, slot + it * 256);
    if (lane < 2) GL16(g4 + 448 + lane, slot + 1792);
}

// dst[h][n] = (|.|) sum_d row[d*15+n]*w[h*3+d] + bb[h]
template <bool ABS>
__device__ __forceinline__ void projr(const float* row, const float w[9], const float bb[3],
                                      float dst[3][15]) {
    #pragma unroll
    for (int n = 0; n < 15; ++n) {
        float x0 = row[n], x1 = row[15 + n], x2 = row[30 + n];
        #pragma unroll
        for (int h = 0; h < 3; ++h) {
            float y = fmaf(x2, w[h*3+2], fmaf(x1, w[h*3+1], fmaf(x0, w[h*3+0], bb[h])));
            dst[h][n] = ABS ? fabsf(y) : y;
        }
    }
}

// PHASE c: counted wait for chunk c; remapped consume (lane = token r (lane&7) x row-pair
// g (lane>>3), rows i0=2g,i1=2g+1); bpermute-route partials to canonical lanes (dest lane
// t pulls row p's value from lane (p>>1)*8+(t&7), which computed token t&7, row-pair p>>1);
// drain DS; issue chunk c+2 into the just-freed slot.
#define PHASE(c, WN) do { \
    WAITVM(WN); \
    { \
      const float* S = ring + (((c) & 1) ? 1800 : 0); \
      const int r = lane & 7, g = lane >> 3; \
      const int i0 = 2 * g, i1 = (2 * g + 1 < 15) ? 2 * g + 1 : 14; \
      const float* D0 = S + r * 225 + i0 * 15; \
      const float* D1 = S + r * 225 + i1 * 15; \
      const int vb = ((c) * 8 + r) * 45; \
      float pc00=0.f,pc01=0.f,pc02=0.f, pc10=0.f,pc11=0.f,pc12=0.f; \
      _Pragma("unroll") \
      for (int j = 0; j < 15; ++j) { \
        float d0 = D0[j], d1 = D1[j]; \
        float v0 = bf2f(vvb[vb + j]); \
        float v1 = bf2f(vvb[vb + 15 + j]); \
        float v2 = bf2f(vvb[vb + 30 + j]); \
        pc00 = fmaf(d0, v0, pc00); pc01 = fmaf(d0, v1, pc01); pc02 = fmaf(d0, v2, pc02); \
        pc10 = fmaf(d1, v0, pc10); pc11 = fmaf(d1, v1, pc11); pc12 = fmaf(d1, v2, pc12); \
      } \
      const bool mine = ((lane >> 3) == (c)); \
      _Pragma("unroll") \
      for (int y = 0; y < 45; ++y) { \
        const int p = y / 3, h = y % 3; \
        int srcl = (((p >> 1) * 8) + (lane & 7)) << 2; \
        float val = (p & 1) ? ((h == 0) ? pc10 : (h == 1) ? pc11 : pc12) \
                            : ((h == 0) ? pc00 : (h == 1) ? pc01 : pc02); \
        int bp = __builtin_amdgcn_ds_bpermute(srcl, __float_as_int(val)); \
        concat[y] += mine ? __int_as_float(bp) : 0.f; \
      } \
    } \
    WAITLG(); \
    if ((c) + 2 <= 7) \
        stage_chunk(dbase + ((c) + 2) * 1800, ring + (((c) & 1) ? 1800 : 0), lane); \
} while (0)

__global__ __launch_bounds__(NT, 2)   // proven regime: VGPR budget 256, no squeeze
void mha_spatial_kernel(
    const float* __restrict__ q, const float* __restrict__ k, const float* __restrict__ v,
    const float* __restrict__ dist,
    const float* __restrict__ Wq, const float* __restrict__ bq,
    const float* __restrict__ Wk, const float* __restrict__ bk,
    const float* __restrict__ Wv, const float* __restrict__ bv,
    const float* __restrict__ Wo, const float* __restrict__ bo,
    float* __restrict__ out)
{
    __shared__ __align__(16) float ring[3600];       // 14.4 KB: qkv staging [0,2880) -> slots B/A
    __shared__ unsigned short vvb[2880];             // 5.76 KB bf16 2*vh table [t][h*15+j]
    // total 20,160 B -> 20,480 rounded -> exactly 8 blocks/CU
    const int lane = threadIdx.x;                    // one wave per block
    const int tokbase = blockIdx.x * TOK;

    // Tiny projection weights via uniform scalar loads. log2(e) folded into Wq/bq
    // (Z-norm cancels scale; |.| commutes); 2x dist factor folded into Wv/bv (rz=0.5/Z).
    const float LOG2E = 1.4426950408889634f;
    float wq[9], wk[9], wv[9], bqv[3], bkv[3], bvv[3];
    #pragma unroll
    for (int i = 0; i < 9; ++i) { wq[i] = Wq[i] * LOG2E; wk[i] = Wk[i]; wv[i] = Wv[i] * 2.f; }
    #pragma unroll
    for (int i = 0; i < 3; ++i) { bqv[i] = bq[i] * LOG2E; bkv[i] = bk[i]; bvv[i] = bv[i] * 2.f; }

    float a[3][15], b[3][15], vv[3][15];

    // ---- prologue: serial q,k,v through ring[0,2880), absolute drains (R6-proven) ----
    stage45(q + (size_t)tokbase * 45, ring, lane);
    WAITVM(0);
    projr<true>(ring + lane * 45, wq, bqv, a);
    WAITLG();
    stage45(k + (size_t)tokbase * 45, ring, lane);
    WAITVM(0);
    projr<true>(ring + lane * 45, wk, bkv, b);
    WAITLG();
    stage45(v + (size_t)tokbase * 45, ring, lane);
    WAITVM(0);
    projr<false>(ring + lane * 45, wv, bvv, vv);     // vv = 2*vh (fp32, in-reg for softmax)
    {   // broadcast vv to bf16 LDS table (only the dist term reads it)
        const int base = lane * 45;
        #pragma unroll
        for (int y = 0; y < 45; ++y) vvb[base + y] = f2bf(vv[y / 15][y % 15]);
    }
    WAITLG();                                        // v reads + table writes drained

    // ---- start the linear dist pipeline: chunks 0,1 fly under the softmax ----
    const float* dbase = dist + (size_t)tokbase * 225;
    stage_chunk(dbase + 0 * 1800, ring,        lane);   // chunk0 -> slotB  [8 out]
    stage_chunk(dbase + 1 * 1800, ring + 1800, lane);   // chunk1 -> slotA  [16 out]

    // ---- softmax + PV in registers ----
    float concat[45];                            // concat[n*3+h]
    #pragma unroll
    for (int h = 0; h < 3; ++h) {
        float zp[4] = {0.f, 0.f, 0.f, 0.f};
        float pv[15];
        #pragma unroll
        for (int i = 0; i < 15; ++i) pv[i] = 0.f;
        #pragma unroll
        for (int i = 0; i < 15; ++i)
            #pragma unroll
            for (int j = 0; j < 15; ++j) {
                float t = EXP2F(fminf(a[h][i] * b[h][j], 88.f));  // clamp: bugs fail finite
                zp[j & 3] += t;
                pv[i] = fmaf(t, vv[h][j], pv[i]);
            }
        const float rz = 0.5f / ((zp[0] + zp[1]) + (zp[2] + zp[3]));
        #pragma unroll
        for (int i = 0; i < 15; ++i) concat[i*3 + h] = pv[i] * rz;
    }

    // ---- 8 linear chunks, ring-2, counted vmcnt (entry: 16 out, oldest 8 = chunk c) ----
    PHASE(0, 8); PHASE(1, 8); PHASE(2, 8); PHASE(3, 8);
    PHASE(4, 8); PHASE(5, 8); PHASE(6, 8); PHASE(7, 0);

    // ---- output projection: Wo/bo via uniform scalar loads ----
    #pragma unroll 3
    for (int o = 0; o < 45; ++o) {
        float acc = bo[o];
        const float* wr = Wo + o * 45;           // uniform address -> s_load
        #pragma unroll
        for (int cc = 0; cc < 45; ++cc) acc = fmaf(concat[cc], wr[cc], acc);
        ring[lane * 45 + o] = acc;               // [0,2880): both slots dead by now
    }
    WAITLG();
    {
        float4* o4 = (float4*)(out + (size_t)tokbase * 45);
        const float4* s4 = (const float4*)ring;
        #pragma unroll
        for (int it = 0; it < 11; ++it) o4[it * 64 + lane] = s4[it * 64 + lane];
        if (lane < 16) o4[704 + lane] = s4[704 + lane];
    }
}

extern "C" void kernel_launch(void* const* d_in, const int* in_sizes, int n_in,
                              void* d_out, int out_size, void* d_ws, size_t ws_size,
                              hipStream_t stream) {
    const float* q  = (const float*)d_in[0];
    const float* k  = (const float*)d_in[1];
    const float* v  = (const float*)d_in[2];
    const float* ds = (const float*)d_in[3];
    const float* Wq = (const float*)d_in[5];
    const float* bq = (const float*)d_in[6];
    const float* Wk = (const float*)d_in[7];
    const float* bk = (const float*)d_in[8];
    const float* Wv = (const float*)d_in[9];
    const float* bv = (const float*)d_in[10];
    const float* Wo = (const float*)d_in[11];
    const float* bo = (const float*)d_in[12];
    float* out = (float*)d_out;

    // att_val = zeros(4096) at the tail of d_out
    hipMemsetAsync(out + (size_t)32 * 4096 * 45, 0, 4096 * sizeof(float), stream);

    mha_spatial_kernel<<<dim3((32 * 4096) / TOK), dim3(NT), 0, stream>>>(
        q, k, v, ds, Wq, bq, Wk, bk, Wv, bv, Wo, bo, out);
}